// Round 4
// baseline (312.781 us; speedup 1.0000x reference)
//
#include <hip/hip_runtime.h>
#include <math.h>

// B=2, T=2048, C=1024, H=16, D=64
typedef short bf8_t __attribute__((ext_vector_type(8)));   // 8 bf16 (4 VGPR)
typedef float f4_t  __attribute__((ext_vector_type(4)));
typedef unsigned int u32;
typedef unsigned short u16;

#define MFMA(a,b,c) __builtin_amdgcn_mfma_f32_16x16x32_bf16((a),(b),(c),0,0,0)

__device__ __forceinline__ void gload16(const void* g, void* l) {
  __builtin_amdgcn_global_load_lds(
      (const __attribute__((address_space(1))) void*)g,
      (__attribute__((address_space(3))) void*)l, 16, 0, 0);
}

__device__ __forceinline__ u16 f2bf(float f) {   // RNE f32->bf16
  u32 u = __float_as_uint(f);
  u += 0x7fff + ((u >> 16) & 1);
  return (u16)(u >> 16);
}

// ---------------------------------------------------------------------------
// 128x128 bf16-MFMA GEMM tile: acc += A * B^T (both row-major [rows][K]).
// ---------------------------------------------------------------------------
__device__ __forceinline__ void gemm_tile(
    const u16* __restrict__ A, const u16* __restrict__ Bm,
    int lda, int ldb, int m0, int n0, int K,
    short* As, short* Bs, f4_t acc[4][4], int tid)
{
  const int lane = tid & 63, w = tid >> 6;
  const int lo = lane & 15, hi = lane >> 4;
  const int wr = (w >> 1) * 64, wc = (w & 1) * 64;
  for (int k0 = 0; k0 < K; k0 += 64) {
    __syncthreads();
#pragma unroll
    for (int iss = 0; iss < 4; ++iss) {
      int bb = iss * 4096 + tid * 16;
      int row = bb >> 7;
      int lg = ((bb >> 4) & 7) ^ (row & 7);
      gload16(A  + (size_t)(m0 + row) * lda + k0 + lg * 8,
              (char*)As + iss * 4096 + w * 1024);
      gload16(Bm + (size_t)(n0 + row) * ldb + k0 + lg * 8,
              (char*)Bs + iss * 4096 + w * 1024);
    }
    __syncthreads();
#pragma unroll
    for (int kk = 0; kk < 2; ++kk) {
      bf8_t af[4], bfr[4];
#pragma unroll
      for (int m = 0; m < 4; ++m) {
        int row = wr + m * 16 + lo;
        int g = (kk * 4 + hi) ^ (row & 7);
        af[m] = *(const bf8_t*)&As[row * 64 + g * 8];
      }
#pragma unroll
      for (int n = 0; n < 4; ++n) {
        int row = wc + n * 16 + lo;
        int g = (kk * 4 + hi) ^ (row & 7);
        bfr[n] = *(const bf8_t*)&Bs[row * 64 + g * 8];
      }
#pragma unroll
      for (int m = 0; m < 4; ++m)
#pragma unroll
        for (int n = 0; n < 4; ++n)
          acc[m][n] = MFMA(af[m], bfr[n], acc[m][n]);
    }
  }
}

// ---------------------------------------------------------------------------
// K1: fp32 -> bf16 conversion of x and weights; zero entropy scalar.
// ---------------------------------------------------------------------------
__global__ __launch_bounds__(256)
void convert_kernel(const float* __restrict__ x,  const float* __restrict__ wq,
                    const float* __restrict__ wk, const float* __restrict__ wv,
                    const float* __restrict__ wo,
                    u16* xb, u16* wqb, u16* wkb, u16* wvb, u16* wob, float* ent)
{
  size_t i = (size_t)blockIdx.x * 256 + threadIdx.x;
  if (blockIdx.x == 0 && threadIdx.x == 0) *ent = 0.f;
  const float* src; u16* dst; size_t off;
  if (i < 524288) { src = x; dst = xb; off = i; }
  else {
    size_t r = i - 524288;
    int sel = (int)(r >> 17);
    off = r & 131071;
    src = sel == 0 ? wq : sel == 1 ? wk : sel == 2 ? wv : wo;
    dst = sel == 0 ? wqb : sel == 1 ? wkb : sel == 2 ? wvb : wob;
  }
  f4_t a = *(const f4_t*)&src[off * 8];
  f4_t c = *(const f4_t*)&src[off * 8 + 4];
  u16 t[8] = {f2bf(a[0]), f2bf(a[1]), f2bf(a[2]), f2bf(a[3]),
              f2bf(c[0]), f2bf(c[1]), f2bf(c[2]), f2bf(c[3])};
  *(uint4*)&dst[off * 8] = *(const uint4*)t;
}

// ---------------------------------------------------------------------------
// K2: fused QKV projection. Q,K -> [B,H,T,D]; V -> TRANSPOSED [B,H,D,T].
// ---------------------------------------------------------------------------
__global__ __launch_bounds__(256)
void qkv_kernel(const u16* __restrict__ X, const u16* __restrict__ Wq,
                const u16* __restrict__ Wk, const u16* __restrict__ Wv,
                const float* __restrict__ bq, const float* __restrict__ bk,
                const float* __restrict__ bv,
                u16* Qo, u16* Ko, u16* Vto)
{
  __shared__ short As[8192], Bs[8192];
  const int tid = threadIdx.x;
  const int nb = blockIdx.x;
  const int which = nb >> 3;
  const int n0 = (nb & 7) * 128;
  const int m0 = blockIdx.y * 128;
  const u16* W    = which == 0 ? Wq : which == 1 ? Wk : Wv;
  const float* bias = which == 0 ? bq : which == 1 ? bk : bv;

  f4_t acc[4][4];
#pragma unroll
  for (int m = 0; m < 4; ++m)
#pragma unroll
    for (int n = 0; n < 4; ++n) acc[m][n] = f4_t{0.f, 0.f, 0.f, 0.f};

  gemm_tile(X, W, 1024, 1024, m0, n0, 1024, As, Bs, acc, tid);

  const int lane = tid & 63, w = tid >> 6;
  const int lo = lane & 15, hi = lane >> 4;
  const int wr = (w >> 1) * 64, wc = (w & 1) * 64;
#pragma unroll
  for (int n = 0; n < 4; ++n) {
    int col = n0 + wc + n * 16 + lo;
    float bb = bias[col];
    int hh = col >> 6, d = col & 63;
#pragma unroll
    for (int m = 0; m < 4; ++m)
#pragma unroll
      for (int j = 0; j < 4; ++j) {
        int row = m0 + wr + m * 16 + hi * 4 + j;
        int bidx = row >> 11, t = row & 2047;
        u16 val = f2bf(acc[m][n][j] + bb);
        if (which < 2) {
          u16* Out = which == 0 ? Qo : Ko;
          Out[(((size_t)bidx * 16 + hh) * 2048 + t) * 64 + d] = val;
        } else {
          Vto[(((size_t)bidx * 16 + hh) * 64 + d) * 2048 + t] = val;
        }
      }
  }
}

// ---------------------------------------------------------------------------
// K3: causal flash attention, 4-way KV-split per 16-row q-group.
// grid = 4096: block n -> bh = (n&7)*4+((n>>3)&3), q-group g = n>>5.
// Each of the 4 waves processes a quarter of the group's KV tiles with
// private online-softmax state; states merge via LDS flash-combine at end.
// K fragments are double-buffer prefetched; V^T frags issue early (hidden
// under QK+softmax). P round-trips a per-wave swizzled 2KB LDS strip.
// ---------------------------------------------------------------------------
__global__ __launch_bounds__(256)
void attn_kernel(const u16* __restrict__ Qg, const u16* __restrict__ Kg,
                 const u16* __restrict__ Vtg, u16* __restrict__ Att,
                 float* __restrict__ Ent)
{
  __shared__ short Ps[4][1024];          // per-wave P strip [16 q][64 kv]
  __shared__ f4_t  Om[3][64][4];         // secondary waves' o-state
  __shared__ float Ms[3][64], Ls[3][64], Es[3][64];

  const int tid = threadIdx.x, lane = tid & 63, w = tid >> 6;
  const int lo = lane & 15, hi = lane >> 4;
  const int n = blockIdx.x;
  const int bh = (n & 7) * 4 + ((n >> 3) & 3);
  const int g = n >> 5;                  // q-group within head, 0..127
  const int b = bh >> 4, h = bh & 15;
  const int q0 = g * 16;
  const u16* Qb  = Qg  + (size_t)bh * (2048 * 64);
  const u16* Kb  = Kg  + (size_t)bh * (2048 * 64);
  const u16* Vtb = Vtg + (size_t)bh * (64 * 2048);
  u16* Attp = Att + (size_t)b * (2048 * 1024) + h * 64;
  short* Pw = Ps[w];

  // KV range split across the 4 waves
  const int nt = (g >> 2) + 1;           // total 64-wide KV tiles
  const int base = nt >> 2, rem = nt & 3;
  const int cnt = base + (w < rem ? 1 : 0);
  const int kts = w * base + (w < rem ? w : rem);

  // Q fragments (B-operand): n = q0+lo, k = d
  bf8_t qf[2];
#pragma unroll
  for (int kk = 0; kk < 2; ++kk)
    qf[kk] = *(const bf8_t*)&Qb[(size_t)(q0 + lo) * 64 + kk * 32 + hi * 8];

  f4_t o[4];
#pragma unroll
  for (int md = 0; md < 4; ++md) o[md] = f4_t{0.f, 0.f, 0.f, 0.f};
  float m_ = -3.0e38f, l_ = 0.f, E_ = 0.f;

  bf8_t kA[4][2], kB[4][2];
  auto ldK = [&](int kt, bf8_t (&kf)[4][2]) {
    const u16* Kt = Kb + (size_t)kt * (64 * 64);
#pragma unroll
    for (int mk = 0; mk < 4; ++mk)
#pragma unroll
      for (int kk = 0; kk < 2; ++kk)
        kf[mk][kk] = *(const bf8_t*)&Kt[(mk * 16 + lo) * 64 + kk * 32 + hi * 8];
  };

  auto tilebody = [&](bf8_t (&kf)[4][2], int kt) {
    // V^T frags for this tile (consumed after softmax -> latency hidden)
    bf8_t vf[4][2];
#pragma unroll
    for (int md = 0; md < 4; ++md)
#pragma unroll
      for (int kh = 0; kh < 2; ++kh)
        vf[md][kh] = *(const bf8_t*)
            &Vtb[(size_t)(md * 16 + lo) * 2048 + kt * 64 + kh * 32 + hi * 8];

    // S' = K . Q^T : s[mk][j] at kv = kt*64 + mk*16 + hi*4 + j, q = q0 + lo
    f4_t s[4];
#pragma unroll
    for (int mk = 0; mk < 4; ++mk) s[mk] = f4_t{0.f, 0.f, 0.f, 0.f};
#pragma unroll
    for (int kk = 0; kk < 2; ++kk)
#pragma unroll
      for (int mk = 0; mk < 4; ++mk)
        s[mk] = MFMA(kf[mk][kk], qf[kk], s[mk]);

    const bool dm = (kt == nt - 1);      // only last global tile straddles diag
#pragma unroll
    for (int mk = 0; mk < 4; ++mk)
#pragma unroll
      for (int jj = 0; jj < 4; ++jj) {
        float sv = s[mk][jj] * 0.125f;
        if (dm && (kt * 64 + mk * 16 + hi * 4 + jj) > (q0 + lo)) sv = -1.0e30f;
        s[mk][jj] = sv;
      }

    // online softmax for the lane-local q row (16 vals + 2 shfl steps)
    float mt = s[0][0];
#pragma unroll
    for (int mk = 0; mk < 4; ++mk)
#pragma unroll
      for (int jj = 0; jj < 4; ++jj) mt = fmaxf(mt, s[mk][jj]);
    mt = fmaxf(mt, __shfl_xor(mt, 16));
    mt = fmaxf(mt, __shfl_xor(mt, 32));
    float mnew = fmaxf(m_, mt);
    float f = __expf(m_ - mnew);         // 0 on first tile
    float p[16], lt = 0.f, Et = 0.f;
#pragma unroll
    for (int mk = 0; mk < 4; ++mk)
#pragma unroll
      for (int jj = 0; jj < 4; ++jj) {
        float pv = __expf(s[mk][jj] - mnew);
        p[mk * 4 + jj] = pv;
        lt += pv; Et += pv * s[mk][jj];  // 0 * -1e30 == -0, no NaN
      }
    lt += __shfl_xor(lt, 16); lt += __shfl_xor(lt, 32);
    Et += __shfl_xor(Et, 16); Et += __shfl_xor(Et, 32);
    l_ = l_ * f + lt; E_ = E_ * f + Et; m_ = mnew;
#pragma unroll
    for (int md = 0; md < 4; ++md) o[md] *= f;

    // P^T row (q=lo) -> per-wave LDS strip, 16B-granule XOR swizzle
#pragma unroll
    for (int mk = 0; mk < 4; ++mk) {
      u32 l32 = (u32)f2bf(p[mk * 4 + 0]) | ((u32)f2bf(p[mk * 4 + 1]) << 16);
      u32 h32 = (u32)f2bf(p[mk * 4 + 2]) | ((u32)f2bf(p[mk * 4 + 3]) << 16);
      int gg = (mk * 2 + (hi >> 1)) ^ (lo & 7);
      *(uint2*)&Pw[lo * 64 + gg * 8 + (hi & 1) * 4] = make_uint2(l32, h32);
    }

    // PV (swapped): o[md] += V^T(d x kv) . P^T(kv x q)
#pragma unroll
    for (int kh = 0; kh < 2; ++kh) {
      int gg = (kh * 4 + hi) ^ (lo & 7);
      bf8_t pf = *(const bf8_t*)&Pw[lo * 64 + gg * 8];
#pragma unroll
      for (int md = 0; md < 4; ++md)
        o[md] = MFMA(vf[md][kh], pf, o[md]);
    }
  };

  // main loop: K double-buffer prefetch, parity-selected named buffers
  if (cnt > 0) ldK(kts, kA);
  for (int i = 0; i < cnt; ++i) {
    int kt = kts + i;
    if ((i & 1) == 0) {
      if (i + 1 < cnt) ldK(kt + 1, kB);
      tilebody(kA, kt);
    } else {
      if (i + 1 < cnt) ldK(kt + 1, kA);
      tilebody(kB, kt);
    }
  }

  // publish secondary states, merge on wave 0 (flash combine)
  if (w > 0) {
#pragma unroll
    for (int md = 0; md < 4; ++md) Om[w - 1][lane][md] = o[md];
    Ms[w - 1][lane] = m_; Ls[w - 1][lane] = l_; Es[w - 1][lane] = E_;
  }
  __syncthreads();
  if (w == 0) {
    float mm = m_;
#pragma unroll
    for (int s2 = 0; s2 < 3; ++s2) mm = fmaxf(mm, Ms[s2][lane]);
    float f0 = __expf(m_ - mm);          // empty-wave partners give f=0
    float lM = l_ * f0, EM = E_ * f0;
    f4_t oM[4];
#pragma unroll
    for (int md = 0; md < 4; ++md) oM[md] = o[md] * f0;
#pragma unroll
    for (int s2 = 0; s2 < 3; ++s2) {
      float fs = __expf(Ms[s2][lane] - mm);
      lM += Ls[s2][lane] * fs;
      EM += Es[s2][lane] * fs;
#pragma unroll
      for (int md = 0; md < 4; ++md) oM[md] += Om[s2][lane][md] * fs;
    }
    float invl = 1.0f / lM;
#pragma unroll
    for (int md = 0; md < 4; ++md) {
      u32 w0 = (u32)f2bf(oM[md][0] * invl) | ((u32)f2bf(oM[md][1] * invl) << 16);
      u32 w1 = (u32)f2bf(oM[md][2] * invl) | ((u32)f2bf(oM[md][3] * invl) << 16);
      *(uint2*)&Attp[(size_t)(q0 + lo) * 1024 + md * 16 + hi * 4] =
          make_uint2(w0, w1);
    }
    // entropy: H = m + log(l) - E/l ; one contributor per row (hi==0)
    float hs = (hi == 0) ? (mm + __logf(lM) - EM * invl) : 0.f;
#pragma unroll
    for (int off = 1; off < 64; off <<= 1) hs += __shfl_xor(hs, off);
    if (lane == 0) atomicAdd(Ent, hs * (1.0f / 65536.0f));
  }
}

// ---------------------------------------------------------------------------
// K4: output projection (bf16 MFMA), fp32 output. grid = (8, 32).
// ---------------------------------------------------------------------------
__global__ __launch_bounds__(256)
void proj_kernel(const u16* __restrict__ Attb, const u16* __restrict__ Wo,
                 const float* __restrict__ bo, float* __restrict__ Out)
{
  __shared__ short As[8192], Bs[8192];
  const int tid = threadIdx.x;
  const int n0 = blockIdx.x * 128;
  const int m0 = blockIdx.y * 128;

  f4_t acc[4][4];
#pragma unroll
  for (int m = 0; m < 4; ++m)
#pragma unroll
    for (int n = 0; n < 4; ++n) acc[m][n] = f4_t{0.f, 0.f, 0.f, 0.f};

  gemm_tile(Attb, Wo, 1024, 1024, m0, n0, 1024, As, Bs, acc, tid);

  const int lane = tid & 63, w = tid >> 6;
  const int lo = lane & 15, hi = lane >> 4;
  const int wr = (w >> 1) * 64, wc = (w & 1) * 64;
#pragma unroll
  for (int n = 0; n < 4; ++n) {
    int col = n0 + wc + n * 16 + lo;
    float bb = bo[col];
#pragma unroll
    for (int m = 0; m < 4; ++m)
#pragma unroll
      for (int j = 0; j < 4; ++j) {
        int row = m0 + wr + m * 16 + hi * 4 + j;
        Out[(size_t)row * 1024 + col] = acc[m][n][j] + bb;
      }
  }
}

// ---------------------------------------------------------------------------
extern "C" void kernel_launch(void* const* d_in, const int* in_sizes, int n_in,
                              void* d_out, int out_size, void* d_ws, size_t ws_size,
                              hipStream_t stream)
{
  const float* x  = (const float*)d_in[0];
  // d_in[1] = causal mask (structure hard-coded)
  const float* wq = (const float*)d_in[2];
  const float* bq = (const float*)d_in[3];
  const float* wk = (const float*)d_in[4];
  const float* bk = (const float*)d_in[5];
  const float* wv = (const float*)d_in[6];
  const float* bv = (const float*)d_in[7];
  const float* wo = (const float*)d_in[8];
  const float* bo = (const float*)d_in[9];

  float* out = (float*)d_out;
  float* ent = out + (size_t)2 * 2048 * 1024;

  char* ws = (char*)d_ws;
  u16* xb   = (u16*)ws;                               // 8 MB  (4096x1024)
  u16* wqb  = (u16*)(ws + 8388608);                   // 2 MB each
  u16* wkb  = (u16*)(ws + 8388608 + 2097152);
  u16* wvb  = (u16*)(ws + 8388608 + 2 * 2097152);
  u16* wob  = (u16*)(ws + 8388608 + 3 * 2097152);
  u16* Qb   = (u16*)(ws + 16777216);                  // 8 MB, [B,H,T,D]
  u16* Kb   = (u16*)(ws + 16777216 + 8388608);        // 8 MB, [B,H,T,D]
  u16* Vtb  = (u16*)(ws + 16777216 + 2 * 8388608);    // 8 MB, [B,H,D,T]
  u16* Attb = (u16*)(ws + 16777216 + 3 * 8388608);    // 8 MB, [B,T,C]

  convert_kernel<<<4096, 256, 0, stream>>>(x, wq, wk, wv, wo,
                                           xb, wqb, wkb, wvb, wob, ent);
  qkv_kernel<<<dim3(24, 32), 256, 0, stream>>>(xb, wqb, wkb, wvb,
                                               bq, bk, bv, Qb, Kb, Vtb);
  attn_kernel<<<4096, 256, 0, stream>>>(Qb, Kb, Vtb, Attb, ent);
  proj_kernel<<<dim3(8, 32), 256, 0, stream>>>(Attb, wob, bo, out);
}

// Round 5
// 239.602 us; speedup vs baseline: 1.3054x; 1.3054x over previous
//
#include <hip/hip_runtime.h>
#include <math.h>

// B=2, T=2048, C=1024, H=16, D=64
typedef short bf8_t __attribute__((ext_vector_type(8)));   // 8 bf16 (4 VGPR)
typedef float f4_t  __attribute__((ext_vector_type(4)));
typedef unsigned int u32;
typedef unsigned short u16;

#define MFMA(a,b,c) __builtin_amdgcn_mfma_f32_16x16x32_bf16((a),(b),(c),0,0,0)

__device__ __forceinline__ void gload16(const void* g, void* l) {
  __builtin_amdgcn_global_load_lds(
      (const __attribute__((address_space(1))) void*)g,
      (__attribute__((address_space(3))) void*)l, 16, 0, 0);
}

__device__ __forceinline__ u16 f2bf(float f) {   // RNE f32->bf16
  u32 u = __float_as_uint(f);
  u += 0x7fff + ((u >> 16) & 1);
  return (u16)(u >> 16);
}

// packed f32x2 -> bf16x2 (RNE), one VALU op
__device__ __forceinline__ u32 cvtpk(float a, float b) {
  u32 r;
  asm("v_cvt_pk_bf16_f32 %0, %1, %2" : "=v"(r) : "v"(a), "v"(b));
  return r;
}

// ---------------------------------------------------------------------------
// 128x128 bf16-MFMA GEMM tile: acc += A * B^T (both row-major [rows][K]).
// ---------------------------------------------------------------------------
__device__ __forceinline__ void gemm_tile(
    const u16* __restrict__ A, const u16* __restrict__ Bm,
    int lda, int ldb, int m0, int n0, int K,
    short* As, short* Bs, f4_t acc[4][4], int tid)
{
  const int lane = tid & 63, w = tid >> 6;
  const int lo = lane & 15, hi = lane >> 4;
  const int wr = (w >> 1) * 64, wc = (w & 1) * 64;
  for (int k0 = 0; k0 < K; k0 += 64) {
    __syncthreads();
#pragma unroll
    for (int iss = 0; iss < 4; ++iss) {
      int bb = iss * 4096 + tid * 16;
      int row = bb >> 7;
      int lg = ((bb >> 4) & 7) ^ (row & 7);
      gload16(A  + (size_t)(m0 + row) * lda + k0 + lg * 8,
              (char*)As + iss * 4096 + w * 1024);
      gload16(Bm + (size_t)(n0 + row) * ldb + k0 + lg * 8,
              (char*)Bs + iss * 4096 + w * 1024);
    }
    __syncthreads();
#pragma unroll
    for (int kk = 0; kk < 2; ++kk) {
      bf8_t af[4], bfr[4];
#pragma unroll
      for (int m = 0; m < 4; ++m) {
        int row = wr + m * 16 + lo;
        int g = (kk * 4 + hi) ^ (row & 7);
        af[m] = *(const bf8_t*)&As[row * 64 + g * 8];
      }
#pragma unroll
      for (int n = 0; n < 4; ++n) {
        int row = wc + n * 16 + lo;
        int g = (kk * 4 + hi) ^ (row & 7);
        bfr[n] = *(const bf8_t*)&Bs[row * 64 + g * 8];
      }
#pragma unroll
      for (int m = 0; m < 4; ++m)
#pragma unroll
        for (int n = 0; n < 4; ++n)
          acc[m][n] = MFMA(af[m], bfr[n], acc[m][n]);
    }
  }
}

// ---------------------------------------------------------------------------
// K1: fp32 -> bf16 conversion of x and weights; zero entropy scalar.
// ---------------------------------------------------------------------------
__global__ __launch_bounds__(256)
void convert_kernel(const float* __restrict__ x,  const float* __restrict__ wq,
                    const float* __restrict__ wk, const float* __restrict__ wv,
                    const float* __restrict__ wo,
                    u16* xb, u16* wqb, u16* wkb, u16* wvb, u16* wob, float* ent)
{
  size_t i = (size_t)blockIdx.x * 256 + threadIdx.x;
  if (blockIdx.x == 0 && threadIdx.x == 0) *ent = 0.f;
  const float* src; u16* dst; size_t off;
  if (i < 524288) { src = x; dst = xb; off = i; }
  else {
    size_t r = i - 524288;
    int sel = (int)(r >> 17);
    off = r & 131071;
    src = sel == 0 ? wq : sel == 1 ? wk : sel == 2 ? wv : wo;
    dst = sel == 0 ? wqb : sel == 1 ? wkb : sel == 2 ? wvb : wob;
  }
  f4_t a = *(const f4_t*)&src[off * 8];
  f4_t c = *(const f4_t*)&src[off * 8 + 4];
  u16 t[8] = {f2bf(a[0]), f2bf(a[1]), f2bf(a[2]), f2bf(a[3]),
              f2bf(c[0]), f2bf(c[1]), f2bf(c[2]), f2bf(c[3])};
  *(uint4*)&dst[off * 8] = *(const uint4*)t;
}

// ---------------------------------------------------------------------------
// K2: fused QKV projection. Q (pre-scaled by 1/8), K -> [B,H,T,D];
// V -> transposed [B,H,D,T]. Epilogue goes through swizzled LDS so all
// global stores are coalesced 16B chunks.
// ---------------------------------------------------------------------------
__global__ __launch_bounds__(256)
void qkv_kernel(const u16* __restrict__ X, const u16* __restrict__ Wq,
                const u16* __restrict__ Wk, const u16* __restrict__ Wv,
                const float* __restrict__ bq, const float* __restrict__ bk,
                const float* __restrict__ bv,
                u16* Qo, u16* Ko, u16* Vto)
{
  __shared__ short smem[16384];            // 32KB: GEMM staging, then epilogue
  short* As = smem;
  short* Bs = smem + 8192;
  const int tid = threadIdx.x;
  const int nb = blockIdx.x;
  const int which = nb >> 3;
  const int n0 = (nb & 7) * 128;
  const int m0 = blockIdx.y * 128;
  const u16* W    = which == 0 ? Wq : which == 1 ? Wk : Wv;
  const float* bias = which == 0 ? bq : which == 1 ? bk : bv;

  f4_t acc[4][4];
#pragma unroll
  for (int m = 0; m < 4; ++m)
#pragma unroll
    for (int n = 0; n < 4; ++n) acc[m][n] = f4_t{0.f, 0.f, 0.f, 0.f};

  gemm_tile(X, W, 1024, 1024, m0, n0, 1024, As, Bs, acc, tid);
  __syncthreads();                          // all waves done reading As/Bs

  const int lane = tid & 63, w = tid >> 6;
  const int lo = lane & 15, hi = lane >> 4;
  const int wr = (w >> 1) * 64, wc = (w & 1) * 64;
  const float scl = (which == 0) ? 0.125f : 1.0f;   // fold att scale into Q
  char* ep = (char*)smem;
  const int bix = m0 >> 11, t0g = m0 & 2047;

  if (which < 2) {
    // stage [token r][feature c] bf16, 16B-granule XOR swizzle by (r&7)<<1
#pragma unroll
    for (int n = 0; n < 4; ++n) {
      int c = wc + n * 16 + lo;
      float bb = bias[n0 + c];
#pragma unroll
      for (int m = 0; m < 4; ++m)
#pragma unroll
        for (int j = 0; j < 4; ++j) {
          int r = wr + m * 16 + hi * 4 + j;
          int pg = (c >> 3) ^ ((r & 7) << 1);
          *(u16*)(ep + r * 256 + pg * 16 + (c & 7) * 2) =
              f2bf((acc[m][n][j] + bb) * scl);
        }
    }
    __syncthreads();
    u16* Out = (which == 0) ? Qo : Ko;
#pragma unroll
    for (int rep = 0; rep < 8; ++rep) {
      int r = rep * 16 + (tid >> 4);
      int seg = tid & 15;
      int pg = seg ^ ((r & 7) << 1);
      uint4 v = *(uint4*)(ep + r * 256 + pg * 16);  // cols seg*8..+7
      int hh = (n0 >> 6) + (seg >> 3);
      int d = (seg & 7) * 8;
      *(uint4*)&Out[(((size_t)bix * 16 + hh) * 2048 + t0g + r) * 64 + d] = v;
    }
  } else {
    // stage TRANSPOSED [feature c][token r] bf16 (pairs of tokens packed)
#pragma unroll
    for (int n = 0; n < 4; ++n) {
      int c = wc + n * 16 + lo;
      float bb = bias[n0 + c];
#pragma unroll
      for (int m = 0; m < 4; ++m)
#pragma unroll
        for (int jp = 0; jp < 2; ++jp) {
          int r = wr + m * 16 + hi * 4 + jp * 2;       // even
          u32 pk = cvtpk(acc[m][n][jp * 2] + bb, acc[m][n][jp * 2 + 1] + bb);
          int pg = (r >> 3) ^ ((c & 7) << 1);
          *(u32*)(ep + c * 256 + pg * 16 + (r & 7) * 2) = pk;
        }
    }
    __syncthreads();
#pragma unroll
    for (int rep = 0; rep < 8; ++rep) {
      int c = rep * 16 + (tid >> 4);
      int seg = tid & 15;
      int pg = seg ^ ((c & 7) << 1);
      uint4 v = *(uint4*)(ep + c * 256 + pg * 16);  // tokens seg*8..+7
      int f = n0 + c;
      int hh = f >> 6, d = f & 63;
      *(uint4*)&Vto[(((size_t)bix * 16 + hh) * 64 + d) * 2048 + t0g + seg * 8] = v;
    }
  }
}

// ---------------------------------------------------------------------------
// K3: causal flash attention. grid = 1024: block = (bh, 64 q-rows), heavy
// q-tiles first, 4 bh per XCD. 4 waves share double-buffered K/V^T LDS tiles
// (global_load_lds, XOR-swizzled both sides). Swapped QK^T / PV keeps the
// softmax state lane-local; defer-max skips most rescales; Q pre-scaled.
// ---------------------------------------------------------------------------
__global__ __launch_bounds__(256, 4)
void attn_kernel(const u16* __restrict__ Qg, const u16* __restrict__ Kg,
                 const u16* __restrict__ Vtg, u16* __restrict__ Att,
                 float* __restrict__ Ent)
{
  __shared__ char smem[40960];   // K dbuf 16K | V dbuf 16K | P strips 8K
  const int tid = threadIdx.x, lane = tid & 63, w = tid >> 6;
  const int lo = lane & 15, hi = lane >> 4;
  const int n = blockIdx.x;
  const int bh = (n & 7) * 4 + ((n >> 3) & 3);
  const int g64 = 31 - (n >> 5);           // heavy blocks dispatch first
  const int q0 = g64 * 64;
  const int nt = g64 + 1;
  const int b = bh >> 4, h = bh & 15;
  const u16* Qb  = Qg  + (size_t)bh * (2048 * 64);
  const u16* Kb  = Kg  + (size_t)bh * (2048 * 64);
  const u16* Vtb = Vtg + (size_t)bh * (64 * 2048);
  u16* Attp = Att + (size_t)b * (2048 * 1024) + h * 64;
  short* Pw = (short*)(smem + 32768 + w * 2048);   // [16 q][64 kv]

  const int qrow = q0 + w * 16 + lo;       // lane-local q row
  bf8_t qf[2];
#pragma unroll
  for (int kk = 0; kk < 2; ++kk)
    qf[kk] = *(const bf8_t*)&Qb[(size_t)qrow * 64 + kk * 32 + hi * 8];

  f4_t o[4];
#pragma unroll
  for (int md = 0; md < 4; ++md) o[md] = f4_t{0.f, 0.f, 0.f, 0.f};
  float m_ = -3.0e38f, l_ = 0.f, E_ = 0.f;

  auto STAGE = [&](int kt, int buf) {
#pragma unroll
    for (int iss = 0; iss < 2; ++iss) {
      int bb = iss * 4096 + tid * 16;
      int row = bb >> 7;                   // 0..63
      int lg = ((bb >> 4) & 7) ^ (row & 7);
      gload16(Kb + (size_t)(kt * 64 + row) * 64 + lg * 8,
              smem + buf * 8192 + iss * 4096 + w * 1024);
      gload16(Vtb + (size_t)row * 2048 + kt * 64 + lg * 8,
              smem + 16384 + buf * 8192 + iss * 4096 + w * 1024);
    }
  };

  STAGE(0, 0);
  __syncthreads();                         // implicit vmcnt(0) drain
  int cur = 0;

  for (int kt = 0; kt < nt; ++kt) {
    if (kt + 1 < nt) STAGE(kt + 1, cur ^ 1);
    const short* KL = (const short*)(smem + cur * 8192);
    const short* VL = (const short*)(smem + 16384 + cur * 8192);

    // S' = K.Q^T: s[mk][j] at kv-local = mk*16+hi*4+j, q = qrow
    f4_t s[4];
#pragma unroll
    for (int mk = 0; mk < 4; ++mk) s[mk] = f4_t{0.f, 0.f, 0.f, 0.f};
#pragma unroll
    for (int kk = 0; kk < 2; ++kk) {
      bf8_t kf[4];
#pragma unroll
      for (int mk = 0; mk < 4; ++mk) {
        int row = mk * 16 + lo;
        int gg = (kk * 4 + hi) ^ (row & 7);
        kf[mk] = *(const bf8_t*)&KL[row * 64 + gg * 8];
      }
#pragma unroll
      for (int mk = 0; mk < 4; ++mk)
        s[mk] = MFMA(kf[mk], qf[kk], s[mk]);
    }

    // causal mask: only the last tile straddles the diagonal
    if (kt == nt - 1) {
#pragma unroll
      for (int mk = 0; mk < 4; ++mk)
#pragma unroll
        for (int jj = 0; jj < 4; ++jj)
          if ((mk * 16 + hi * 4 + jj) > (w * 16 + lo)) s[mk][jj] = -1.0e30f;
    }

    // online softmax, lane-local q row; defer-max (THR=8)
    float mt = s[0][0];
#pragma unroll
    for (int mk = 0; mk < 4; ++mk)
#pragma unroll
      for (int jj = 0; jj < 4; ++jj) mt = fmaxf(mt, s[mk][jj]);
    mt = fmaxf(mt, __shfl_xor(mt, 16));
    mt = fmaxf(mt, __shfl_xor(mt, 32));
    if (!__all(mt <= m_ + 8.f)) {
      float mnew = fmaxf(m_, mt);
      float f = __expf(m_ - mnew);         // 0 on first tile
      l_ *= f; E_ *= f;
#pragma unroll
      for (int md = 0; md < 4; ++md) o[md] *= f;
      m_ = mnew;
    }
    float p[16], lt = 0.f, Et = 0.f;
#pragma unroll
    for (int mk = 0; mk < 4; ++mk)
#pragma unroll
      for (int jj = 0; jj < 4; ++jj) {
        float pv = __expf(s[mk][jj] - m_);  // bounded by e^8
        p[mk * 4 + jj] = pv;
        lt += pv; Et += pv * s[mk][jj];     // 0 * -1e30 == -0, no NaN
      }
    lt += __shfl_xor(lt, 16); lt += __shfl_xor(lt, 32);
    Et += __shfl_xor(Et, 16); Et += __shfl_xor(Et, 32);
    l_ += lt; E_ += Et;

    // P^T row (q=lo) -> per-wave LDS strip (packed, swizzled)
#pragma unroll
    for (int mk = 0; mk < 4; ++mk) {
      u32 a = cvtpk(p[mk * 4 + 0], p[mk * 4 + 1]);
      u32 c = cvtpk(p[mk * 4 + 2], p[mk * 4 + 3]);
      int gg = (mk * 2 + (hi >> 1)) ^ (lo & 7);
      *(uint2*)&Pw[lo * 64 + gg * 8 + (hi & 1) * 4] = make_uint2(a, c);
    }

    // PV (swapped): o[md] += V^T(d x kv) . P^T(kv x q)
#pragma unroll
    for (int kh = 0; kh < 2; ++kh) {
      int gp = (kh * 4 + hi) ^ (lo & 7);
      bf8_t pf = *(const bf8_t*)&Pw[lo * 64 + gp * 8];
#pragma unroll
      for (int md = 0; md < 4; ++md) {
        int row = md * 16 + lo;
        int gv = (kh * 4 + hi) ^ (row & 7);
        bf8_t vf = *(const bf8_t*)&VL[row * 64 + gv * 8];
        o[md] = MFMA(vf, pf, o[md]);
      }
    }
    __syncthreads();                       // drains prefetch + guards dbuf
    cur ^= 1;
  }

  // epilogue: normalize + bf16 store (8B per lane per md)
  float invl = 1.0f / l_;
#pragma unroll
  for (int md = 0; md < 4; ++md) {
    u32 w0 = cvtpk(o[md][0] * invl, o[md][1] * invl);
    u32 w1 = cvtpk(o[md][2] * invl, o[md][3] * invl);
    *(uint2*)&Attp[(size_t)qrow * 1024 + md * 16 + hi * 4] = make_uint2(w0, w1);
  }
  // entropy: H = m + log(l) - E/l per row; one contributor per row (hi==0)
  float hs = (hi == 0) ? (m_ + __logf(l_) - E_ * invl) : 0.f;
#pragma unroll
  for (int off = 1; off < 64; off <<= 1) hs += __shfl_xor(hs, off);
  if (lane == 0) atomicAdd(Ent, hs * (1.0f / 65536.0f));
}

// ---------------------------------------------------------------------------
// K4: output projection, fp32 out. Two-pass LDS-transposed epilogue so
// stores are coalesced 16B. grid = (8, 32).
// ---------------------------------------------------------------------------
__global__ __launch_bounds__(256)
void proj_kernel(const u16* __restrict__ Attb, const u16* __restrict__ Wo,
                 const float* __restrict__ bo, float* __restrict__ Out)
{
  __shared__ short smem[16384];
  short* As = smem;
  short* Bs = smem + 8192;
  const int tid = threadIdx.x;
  const int n0 = blockIdx.x * 128;
  const int m0 = blockIdx.y * 128;

  f4_t acc[4][4];
#pragma unroll
  for (int m = 0; m < 4; ++m)
#pragma unroll
    for (int n = 0; n < 4; ++n) acc[m][n] = f4_t{0.f, 0.f, 0.f, 0.f};

  gemm_tile(Attb, Wo, 1024, 1024, m0, n0, 1024, As, Bs, acc, tid);

  const int lane = tid & 63, w = tid >> 6;
  const int lo = lane & 15, hi = lane >> 4;
  const int wc = (w & 1) * 64;
  float* ep = (float*)smem;                // [64 rows][128 cols] f32 per pass

#pragma unroll
  for (int pass = 0; pass < 2; ++pass) {
    __syncthreads();                       // guards As/Bs (pass 0) / prev pass
    if ((w >> 1) == pass) {
#pragma unroll
      for (int n = 0; n < 4; ++n) {
        int c = wc + n * 16 + lo;
        float bb = bo[n0 + c];
#pragma unroll
        for (int m = 0; m < 4; ++m)
#pragma unroll
          for (int j = 0; j < 4; ++j) {
            int r = m * 16 + hi * 4 + j;   // 0..63
            int pg = (c >> 2) ^ ((r & 7) << 2);
            ep[r * 128 + pg * 4 + (c & 3)] = acc[m][n][j] + bb;
          }
      }
    }
    __syncthreads();
    int r = tid >> 2, q = tid & 3;
#pragma unroll
    for (int i = 0; i < 8; ++i) {
      int g = q * 8 + i;
      int pg = g ^ ((r & 7) << 2);
      f4_t v = *(f4_t*)&ep[r * 128 + pg * 4];
      *(f4_t*)&Out[(size_t)(m0 + pass * 64 + r) * 1024 + n0 + g * 4] = v;
    }
  }
}

// ---------------------------------------------------------------------------
extern "C" void kernel_launch(void* const* d_in, const int* in_sizes, int n_in,
                              void* d_out, int out_size, void* d_ws, size_t ws_size,
                              hipStream_t stream)
{
  const float* x  = (const float*)d_in[0];
  // d_in[1] = causal mask (structure hard-coded)
  const float* wq = (const float*)d_in[2];
  const float* bq = (const float*)d_in[3];
  const float* wk = (const float*)d_in[4];
  const float* bk = (const float*)d_in[5];
  const float* wv = (const float*)d_in[6];
  const float* bv = (const float*)d_in[7];
  const float* wo = (const float*)d_in[8];
  const float* bo = (const float*)d_in[9];

  float* out = (float*)d_out;
  float* ent = out + (size_t)2 * 2048 * 1024;

  char* ws = (char*)d_ws;
  u16* xb   = (u16*)ws;                               // 8 MB  (4096x1024)
  u16* wqb  = (u16*)(ws + 8388608);                   // 2 MB each
  u16* wkb  = (u16*)(ws + 8388608 + 2097152);
  u16* wvb  = (u16*)(ws + 8388608 + 2 * 2097152);
  u16* wob  = (u16*)(ws + 8388608 + 3 * 2097152);
  u16* Qb   = (u16*)(ws + 16777216);                  // 8 MB, [B,H,T,D] (x1/8)
  u16* Kb   = (u16*)(ws + 16777216 + 8388608);        // 8 MB, [B,H,T,D]
  u16* Vtb  = (u16*)(ws + 16777216 + 2 * 8388608);    // 8 MB, [B,H,D,T]
  u16* Attb = (u16*)(ws + 16777216 + 3 * 8388608);    // 8 MB, [B,T,C]

  convert_kernel<<<4096, 256, 0, stream>>>(x, wq, wk, wv, wo,
                                           xb, wqb, wkb, wvb, wob, ent);
  qkv_kernel<<<dim3(24, 32), 256, 0, stream>>>(xb, wqb, wkb, wvb,
                                               bq, bk, bv, Qb, Kb, Vtb);
  attn_kernel<<<1024, 256, 0, stream>>>(Qb, Kb, Vtb, Attb, ent);
  proj_kernel<<<dim3(8, 32), 256, 0, stream>>>(Attb, wob, bo, out);
}

// Round 6
// 222.990 us; speedup vs baseline: 1.4027x; 1.0745x over previous
//
#include <hip/hip_runtime.h>
#include <math.h>

// B=2, T=2048, C=1024, H=16, D=64
typedef short bf8_t __attribute__((ext_vector_type(8)));   // 8 bf16 (4 VGPR)
typedef float f4_t  __attribute__((ext_vector_type(4)));
typedef unsigned int u32;
typedef unsigned short u16;

#define MFMA(a,b,c) __builtin_amdgcn_mfma_f32_16x16x32_bf16((a),(b),(c),0,0,0)

__device__ __forceinline__ void gload16(const void* g, void* l) {
  __builtin_amdgcn_global_load_lds(
      (const __attribute__((address_space(1))) void*)g,
      (__attribute__((address_space(3))) void*)l, 16, 0, 0);
}

__device__ __forceinline__ u16 f2bf(float f) {   // RNE f32->bf16
  u32 u = __float_as_uint(f);
  u += 0x7fff + ((u >> 16) & 1);
  return (u16)(u >> 16);
}

// packed f32x2 -> bf16x2 (RNE), one VALU op
__device__ __forceinline__ u32 cvtpk(float a, float b) {
  u32 r;
  asm("v_cvt_pk_bf16_f32 %0, %1, %2" : "=v"(r) : "v"(a), "v"(b));
  return r;
}

// ---------------------------------------------------------------------------
// 128x128 bf16-MFMA GEMM tile, 2-phase double-buffered: STAGE(t+1) issues
// BEFORE compute(t); one vmcnt(0)-drain barrier per K-step (T3 minimum).
// LDS layout (bytes): A[buf] at buf*16384, B[buf] at 32768 + buf*16384.
// ---------------------------------------------------------------------------
__device__ __forceinline__ void gemm_tile(
    const u16* __restrict__ A, const u16* __restrict__ Bm,
    int lda, int ldb, int m0, int n0, int K,
    short* smem, f4_t acc[4][4], int tid)
{
  const int lane = tid & 63, w = tid >> 6;
  const int lo = lane & 15, hi = lane >> 4;
  const int wr = (w >> 1) * 64, wc = (w & 1) * 64;
  const int nsteps = K >> 6;

  auto STAGE = [&](int step, int buf) {
    int k0 = step * 64;
#pragma unroll
    for (int iss = 0; iss < 4; ++iss) {
      int bb = iss * 4096 + tid * 16;          // linear LDS byte
      int row = bb >> 7;                       // 128 B per row
      int lg = ((bb >> 4) & 7) ^ (row & 7);    // inverse-swizzled src granule
      gload16(A  + (size_t)(m0 + row) * lda + k0 + lg * 8,
              (char*)smem + buf * 16384 + iss * 4096 + w * 1024);
      gload16(Bm + (size_t)(n0 + row) * ldb + k0 + lg * 8,
              (char*)smem + 32768 + buf * 16384 + iss * 4096 + w * 1024);
    }
  };

  STAGE(0, 0);
  __syncthreads();
  int cur = 0;
  for (int step = 0; step < nsteps; ++step) {
    if (step + 1 < nsteps) STAGE(step + 1, cur ^ 1);  // prefetch flies under MFMA
    const short* As = (const short*)((char*)smem + cur * 16384);
    const short* Bs = (const short*)((char*)smem + 32768 + cur * 16384);
#pragma unroll
    for (int kk = 0; kk < 2; ++kk) {
      bf8_t af[4], bfr[4];
#pragma unroll
      for (int m = 0; m < 4; ++m) {
        int row = wr + m * 16 + lo;
        int g = (kk * 4 + hi) ^ (row & 7);
        af[m] = *(const bf8_t*)&As[row * 64 + g * 8];
      }
#pragma unroll
      for (int n = 0; n < 4; ++n) {
        int row = wc + n * 16 + lo;
        int g = (kk * 4 + hi) ^ (row & 7);
        bfr[n] = *(const bf8_t*)&Bs[row * 64 + g * 8];
      }
#pragma unroll
      for (int m = 0; m < 4; ++m)
#pragma unroll
        for (int n = 0; n < 4; ++n)
          acc[m][n] = MFMA(af[m], bfr[n], acc[m][n]);
    }
    __syncthreads();                       // drains prefetch + guards dbuf
    cur ^= 1;
  }
}

// ---------------------------------------------------------------------------
// K1: fp32 -> bf16 conversion of x and weights; zero entropy scalar.
// ---------------------------------------------------------------------------
__global__ __launch_bounds__(256)
void convert_kernel(const float* __restrict__ x,  const float* __restrict__ wq,
                    const float* __restrict__ wk, const float* __restrict__ wv,
                    const float* __restrict__ wo,
                    u16* xb, u16* wqb, u16* wkb, u16* wvb, u16* wob, float* ent)
{
  size_t i = (size_t)blockIdx.x * 256 + threadIdx.x;
  if (blockIdx.x == 0 && threadIdx.x == 0) *ent = 0.f;
  const float* src; u16* dst; size_t off;
  if (i < 524288) { src = x; dst = xb; off = i; }
  else {
    size_t r = i - 524288;
    int sel = (int)(r >> 17);
    off = r & 131071;
    src = sel == 0 ? wq : sel == 1 ? wk : sel == 2 ? wv : wo;
    dst = sel == 0 ? wqb : sel == 1 ? wkb : sel == 2 ? wvb : wob;
  }
  f4_t a = *(const f4_t*)&src[off * 8];
  f4_t c = *(const f4_t*)&src[off * 8 + 4];
  u16 t[8] = {f2bf(a[0]), f2bf(a[1]), f2bf(a[2]), f2bf(a[3]),
              f2bf(c[0]), f2bf(c[1]), f2bf(c[2]), f2bf(c[3])};
  *(uint4*)&dst[off * 8] = *(const uint4*)t;
}

// ---------------------------------------------------------------------------
// K2: fused QKV projection. Q (pre-scaled by 1/8), K -> [B,H,T,D];
// V -> transposed [B,H,D,T]. Epilogue through swizzled LDS, 16B stores.
// ---------------------------------------------------------------------------
__global__ __launch_bounds__(256)
void qkv_kernel(const u16* __restrict__ X, const u16* __restrict__ Wq,
                const u16* __restrict__ Wk, const u16* __restrict__ Wv,
                const float* __restrict__ bq, const float* __restrict__ bk,
                const float* __restrict__ bv,
                u16* Qo, u16* Ko, u16* Vto)
{
  __shared__ short smem[32768];            // 64KB: GEMM dbuf, then epilogue
  const int tid = threadIdx.x;
  const int nb = blockIdx.x;
  const int which = nb >> 3;
  const int n0 = (nb & 7) * 128;
  const int m0 = blockIdx.y * 128;
  const u16* W    = which == 0 ? Wq : which == 1 ? Wk : Wv;
  const float* bias = which == 0 ? bq : which == 1 ? bk : bv;

  f4_t acc[4][4];
#pragma unroll
  for (int m = 0; m < 4; ++m)
#pragma unroll
    for (int n = 0; n < 4; ++n) acc[m][n] = f4_t{0.f, 0.f, 0.f, 0.f};

  gemm_tile(X, W, 1024, 1024, m0, n0, 1024, smem, acc, tid);

  const int lane = tid & 63, w = tid >> 6;
  const int lo = lane & 15, hi = lane >> 4;
  const int wr = (w >> 1) * 64, wc = (w & 1) * 64;
  const float scl = (which == 0) ? 0.125f : 1.0f;   // fold att scale into Q
  char* ep = (char*)smem;
  const int bix = m0 >> 11, t0g = m0 & 2047;

  if (which < 2) {
    // stage [token r][feature c] bf16, 16B-granule XOR swizzle by (r&7)<<1
#pragma unroll
    for (int n = 0; n < 4; ++n) {
      int c = wc + n * 16 + lo;
      float bb = bias[n0 + c];
#pragma unroll
      for (int m = 0; m < 4; ++m)
#pragma unroll
        for (int j = 0; j < 4; ++j) {
          int r = wr + m * 16 + hi * 4 + j;
          int pg = (c >> 3) ^ ((r & 7) << 1);
          *(u16*)(ep + r * 256 + pg * 16 + (c & 7) * 2) =
              f2bf((acc[m][n][j] + bb) * scl);
        }
    }
    __syncthreads();
    u16* Out = (which == 0) ? Qo : Ko;
#pragma unroll
    for (int rep = 0; rep < 8; ++rep) {
      int r = rep * 16 + (tid >> 4);
      int seg = tid & 15;
      int pg = seg ^ ((r & 7) << 1);
      uint4 v = *(uint4*)(ep + r * 256 + pg * 16);  // cols seg*8..+7
      int hh = (n0 >> 6) + (seg >> 3);
      int d = (seg & 7) * 8;
      *(uint4*)&Out[(((size_t)bix * 16 + hh) * 2048 + t0g + r) * 64 + d] = v;
    }
  } else {
    // stage TRANSPOSED [feature c][token r] bf16 (pairs of tokens packed)
#pragma unroll
    for (int n = 0; n < 4; ++n) {
      int c = wc + n * 16 + lo;
      float bb = bias[n0 + c];
#pragma unroll
      for (int m = 0; m < 4; ++m)
#pragma unroll
        for (int jp = 0; jp < 2; ++jp) {
          int r = wr + m * 16 + hi * 4 + jp * 2;       // even
          u32 pk = cvtpk(acc[m][n][jp * 2] + bb, acc[m][n][jp * 2 + 1] + bb);
          int pg = (r >> 3) ^ ((c & 7) << 1);
          *(u32*)(ep + c * 256 + pg * 16 + (r & 7) * 2) = pk;
        }
    }
    __syncthreads();
#pragma unroll
    for (int rep = 0; rep < 8; ++rep) {
      int c = rep * 16 + (tid >> 4);
      int seg = tid & 15;
      int pg = seg ^ ((c & 7) << 1);
      uint4 v = *(uint4*)(ep + c * 256 + pg * 16);  // tokens seg*8..+7
      int f = n0 + c;
      int hh = f >> 6, d = f & 63;
      *(uint4*)&Vto[(((size_t)bix * 16 + hh) * 64 + d) * 2048 + t0g + seg * 8] = v;
    }
  }
}

// ---------------------------------------------------------------------------
// K3: causal flash attention, balanced. grid = 512: block = (bh, q-tile pair
// {p, 31-p}) -> every block stages exactly 33 KV-tiles. 4 waves share
// double-buffered K/V^T LDS (global_load_lds, XOR-swizzled). Swapped QK^T /
// PV keeps softmax state lane-local; l/E reduction deferred out of the loop;
// defer-max skips most rescales; Q pre-scaled by 1/8.
// ---------------------------------------------------------------------------
__global__ __launch_bounds__(256, 4)
void attn_kernel(const u16* __restrict__ Qg, const u16* __restrict__ Kg,
                 const u16* __restrict__ Vtg, u16* __restrict__ Att,
                 float* __restrict__ Ent)
{
  __shared__ char smem[40960];   // K dbuf 16K | V dbuf 16K | P strips 8K
  const int tid = threadIdx.x, lane = tid & 63, w = tid >> 6;
  const int lo = lane & 15, hi = lane >> 4;
  const int n = blockIdx.x;
  const int bh = (n & 7) * 4 + ((n >> 3) & 3);   // 4 heads per XCD
  const int p = n >> 5;                          // 0..15 -> tiles {p, 31-p}
  const int b = bh >> 4, h = bh & 15;
  const u16* Qb  = Qg  + (size_t)bh * (2048 * 64);
  const u16* Kb  = Kg  + (size_t)bh * (2048 * 64);
  const u16* Vtb = Vtg + (size_t)bh * (64 * 2048);
  u16* Attp = Att + (size_t)b * (2048 * 1024) + h * 64;
  short* Pw = (short*)(smem + 32768 + w * 2048);   // [16 q][64 kv]

  auto STAGE = [&](int kt, int buf) {
#pragma unroll
    for (int iss = 0; iss < 2; ++iss) {
      int bb = iss * 4096 + tid * 16;
      int row = bb >> 7;                   // 0..63
      int lg = ((bb >> 4) & 7) ^ (row & 7);
      gload16(Kb + (size_t)(kt * 64 + row) * 64 + lg * 8,
              smem + buf * 8192 + iss * 4096 + w * 1024);
      gload16(Vtb + (size_t)row * 2048 + kt * 64 + lg * 8,
              smem + 16384 + buf * 8192 + iss * 4096 + w * 1024);
    }
  };

  float hs_total = 0.f;

  for (int ph = 0; ph < 2; ++ph) {
    const int g = ph ? (31 - p) : p;
    const int q0 = g * 64;
    const int nt = g + 1;
    const int qrow = q0 + w * 16 + lo;     // lane-local q row

    bf8_t qf[2];
#pragma unroll
    for (int kk = 0; kk < 2; ++kk)
      qf[kk] = *(const bf8_t*)&Qb[(size_t)qrow * 64 + kk * 32 + hi * 8];

    f4_t o[4];
#pragma unroll
    for (int md = 0; md < 4; ++md) o[md] = f4_t{0.f, 0.f, 0.f, 0.f};
    float m_ = -3.0e38f, l_ = 0.f, E_ = 0.f;   // l_, E_ per-lane partials

    STAGE(0, 0);
    __syncthreads();
    int cur = 0;

    for (int kt = 0; kt < nt; ++kt) {
      if (kt + 1 < nt) STAGE(kt + 1, cur ^ 1);
      const short* KL = (const short*)(smem + cur * 8192);
      const short* VL = (const short*)(smem + 16384 + cur * 8192);

      // S' = K.Q^T: s[mk][j] at kv-local = mk*16+hi*4+j, q = qrow
      f4_t s[4];
#pragma unroll
      for (int mk = 0; mk < 4; ++mk) s[mk] = f4_t{0.f, 0.f, 0.f, 0.f};
#pragma unroll
      for (int kk = 0; kk < 2; ++kk) {
        bf8_t kf[4];
#pragma unroll
        for (int mk = 0; mk < 4; ++mk) {
          int row = mk * 16 + lo;
          int gg = (kk * 4 + hi) ^ (row & 7);
          kf[mk] = *(const bf8_t*)&KL[row * 64 + gg * 8];
        }
#pragma unroll
        for (int mk = 0; mk < 4; ++mk)
          s[mk] = MFMA(kf[mk], qf[kk], s[mk]);
      }

      // causal mask: only the last tile straddles the diagonal
      if (kt == nt - 1) {
#pragma unroll
        for (int mk = 0; mk < 4; ++mk)
#pragma unroll
          for (int jj = 0; jj < 4; ++jj)
            if ((mk * 16 + hi * 4 + jj) > (w * 16 + lo)) s[mk][jj] = -1.0e30f;
      }

      // row max (cross-lane) + defer-max rescale (THR=8)
      float mt = s[0][0];
#pragma unroll
      for (int mk = 0; mk < 4; ++mk)
#pragma unroll
        for (int jj = 0; jj < 4; ++jj) mt = fmaxf(mt, s[mk][jj]);
      mt = fmaxf(mt, __shfl_xor(mt, 16));
      mt = fmaxf(mt, __shfl_xor(mt, 32));
      if (!__all(mt <= m_ + 8.f)) {
        float mnew = fmaxf(m_, mt);
        float f = __expf(m_ - mnew);       // 0 on first tile
        l_ *= f; E_ *= f;
#pragma unroll
        for (int md = 0; md < 4; ++md) o[md] *= f;
        m_ = mnew;
      }
      // per-lane partial l/E (cross-lane reduction deferred to phase end)
      float pv16[16];
#pragma unroll
      for (int mk = 0; mk < 4; ++mk)
#pragma unroll
        for (int jj = 0; jj < 4; ++jj) {
          float pv = __expf(s[mk][jj] - m_);   // bounded by e^8
          pv16[mk * 4 + jj] = pv;
          l_ += pv; E_ += pv * s[mk][jj];      // 0 * -1e30 == -0, no NaN
        }

      // P^T row (q=lo) -> per-wave LDS strip (packed, swizzled)
#pragma unroll
      for (int mk = 0; mk < 4; ++mk) {
        u32 a = cvtpk(pv16[mk * 4 + 0], pv16[mk * 4 + 1]);
        u32 c = cvtpk(pv16[mk * 4 + 2], pv16[mk * 4 + 3]);
        int gg = (mk * 2 + (hi >> 1)) ^ (lo & 7);
        *(uint2*)&Pw[lo * 64 + gg * 8 + (hi & 1) * 4] = make_uint2(a, c);
      }

      // PV (swapped): o[md] += V^T(d x kv) . P^T(kv x q)
#pragma unroll
      for (int kh = 0; kh < 2; ++kh) {
        int gp = (kh * 4 + hi) ^ (lo & 7);
        bf8_t pf = *(const bf8_t*)&Pw[lo * 64 + gp * 8];
#pragma unroll
        for (int md = 0; md < 4; ++md) {
          int row = md * 16 + lo;
          int gv = (kh * 4 + hi) ^ (row & 7);
          bf8_t vf = *(const bf8_t*)&VL[row * 64 + gv * 8];
          o[md] = MFMA(vf, pf, o[md]);
        }
      }
      __syncthreads();                     // drains prefetch + guards dbuf
      cur ^= 1;
    }

    // deferred cross-lane l/E reduction (same q row lives in the 4 hi-lanes)
    l_ += __shfl_xor(l_, 16); l_ += __shfl_xor(l_, 32);
    E_ += __shfl_xor(E_, 16); E_ += __shfl_xor(E_, 32);

    // epilogue: normalize + bf16 store (8B per lane per md)
    float invl = 1.0f / l_;
#pragma unroll
    for (int md = 0; md < 4; ++md) {
      u32 w0 = cvtpk(o[md][0] * invl, o[md][1] * invl);
      u32 w1 = cvtpk(o[md][2] * invl, o[md][3] * invl);
      *(uint2*)&Attp[(size_t)qrow * 1024 + md * 16 + hi * 4] =
          make_uint2(w0, w1);
    }
    // entropy: H = m + log(l) - E/l per row; one contributor per row (hi==0)
    hs_total += (hi == 0) ? (m_ + __logf(l_) - E_ * invl) : 0.f;
  }

  float hs = hs_total;
#pragma unroll
  for (int off = 1; off < 64; off <<= 1) hs += __shfl_xor(hs, off);
  if (lane == 0) atomicAdd(Ent, hs * (1.0f / 65536.0f));
}

// ---------------------------------------------------------------------------
// K4: output projection, fp32 out. Two-pass LDS-transposed epilogue so
// stores are coalesced 16B. grid = (8, 32).
// ---------------------------------------------------------------------------
__global__ __launch_bounds__(256)
void proj_kernel(const u16* __restrict__ Attb, const u16* __restrict__ Wo,
                 const float* __restrict__ bo, float* __restrict__ Out)
{
  __shared__ short smem[32768];
  const int tid = threadIdx.x;
  const int n0 = blockIdx.x * 128;
  const int m0 = blockIdx.y * 128;

  f4_t acc[4][4];
#pragma unroll
  for (int m = 0; m < 4; ++m)
#pragma unroll
    for (int n = 0; n < 4; ++n) acc[m][n] = f4_t{0.f, 0.f, 0.f, 0.f};

  gemm_tile(Attb, Wo, 1024, 1024, m0, n0, 1024, smem, acc, tid);

  const int lane = tid & 63, w = tid >> 6;
  const int lo = lane & 15, hi = lane >> 4;
  const int wc = (w & 1) * 64;
  float* ep = (float*)smem;                // [64 rows][128 cols] f32 per pass

#pragma unroll
  for (int pass = 0; pass < 2; ++pass) {
    __syncthreads();                       // guards smem reuse
    if ((w >> 1) == pass) {
#pragma unroll
      for (int n = 0; n < 4; ++n) {
        int c = wc + n * 16 + lo;
        float bb = bo[n0 + c];
#pragma unroll
        for (int m = 0; m < 4; ++m)
#pragma unroll
          for (int j = 0; j < 4; ++j) {
            int r = m * 16 + hi * 4 + j;   // 0..63
            int pg = (c >> 2) ^ ((r & 7) << 2);
            ep[r * 128 + pg * 4 + (c & 3)] = acc[m][n][j] + bb;
          }
      }
    }
    __syncthreads();
    int r = tid >> 2, q = tid & 3;
#pragma unroll
    for (int i = 0; i < 8; ++i) {
      int g = q * 8 + i;
      int pg = g ^ ((r & 7) << 2);
      f4_t v = *(f4_t*)&ep[r * 128 + pg * 4];
      *(f4_t*)&Out[(size_t)(m0 + pass * 64 + r) * 1024 + n0 + g * 4] = v;
    }
  }
}

// ---------------------------------------------------------------------------
extern "C" void kernel_launch(void* const* d_in, const int* in_sizes, int n_in,
                              void* d_out, int out_size, void* d_ws, size_t ws_size,
                              hipStream_t stream)
{
  const float* x  = (const float*)d_in[0];
  // d_in[1] = causal mask (structure hard-coded)
  const float* wq = (const float*)d_in[2];
  const float* bq = (const float*)d_in[3];
  const float* wk = (const float*)d_in[4];
  const float* bk = (const float*)d_in[5];
  const float* wv = (const float*)d_in[6];
  const float* bv = (const float*)d_in[7];
  const float* wo = (const float*)d_in[8];
  const float* bo = (const float*)d_in[9];

  float* out = (float*)d_out;
  float* ent = out + (size_t)2 * 2048 * 1024;

  char* ws = (char*)d_ws;
  u16* xb   = (u16*)ws;                               // 8 MB  (4096x1024)
  u16* wqb  = (u16*)(ws + 8388608);                   // 2 MB each
  u16* wkb  = (u16*)(ws + 8388608 + 2097152);
  u16* wvb  = (u16*)(ws + 8388608 + 2 * 2097152);
  u16* wob  = (u16*)(ws + 8388608 + 3 * 2097152);
  u16* Qb   = (u16*)(ws + 16777216);                  // 8 MB, [B,H,T,D] (x1/8)
  u16* Kb   = (u16*)(ws + 16777216 + 8388608);        // 8 MB, [B,H,T,D]
  u16* Vtb  = (u16*)(ws + 16777216 + 2 * 8388608);    // 8 MB, [B,H,D,T]
  u16* Attb = (u16*)(ws + 16777216 + 3 * 8388608);    // 8 MB, [B,T,C]

  convert_kernel<<<4096, 256, 0, stream>>>(x, wq, wk, wv, wo,
                                           xb, wqb, wkb, wvb, wob, ent);
  qkv_kernel<<<dim3(24, 32), 256, 0, stream>>>(xb, wqb, wkb, wvb,
                                               bq, bk, bv, Qb, Kb, Vtb);
  attn_kernel<<<512, 256, 0, stream>>>(Qb, Kb, Vtb, Attb, ent);
  proj_kernel<<<dim3(8, 32), 256, 0, stream>>>(Attb, wob, bo, out);
}

// Round 7
// 220.469 us; speedup vs baseline: 1.4187x; 1.0114x over previous
//
#include <hip/hip_runtime.h>
#include <math.h>

// B=2, T=2048, C=1024, H=16, D=64
typedef short bf8_t __attribute__((ext_vector_type(8)));   // 8 bf16 (4 VGPR)
typedef float f4_t  __attribute__((ext_vector_type(4)));
typedef unsigned int u32;
typedef unsigned short u16;

#define MFMA(a,b,c) __builtin_amdgcn_mfma_f32_16x16x32_bf16((a),(b),(c),0,0,0)

__device__ __forceinline__ void gload16(const void* g, void* l) {
  __builtin_amdgcn_global_load_lds(
      (const __attribute__((address_space(1))) void*)g,
      (__attribute__((address_space(3))) void*)l, 16, 0, 0);
}

__device__ __forceinline__ u16 f2bf(float f) {   // RNE f32->bf16
  u32 u = __float_as_uint(f);
  u += 0x7fff + ((u >> 16) & 1);
  return (u16)(u >> 16);
}

// packed f32x2 -> bf16x2 (RNE), one VALU op
__device__ __forceinline__ u32 cvtpk(float a, float b) {
  u32 r;
  asm("v_cvt_pk_bf16_f32 %0, %1, %2" : "=v"(r) : "v"(a), "v"(b));
  return r;
}

// ---------------------------------------------------------------------------
// 128x128 bf16-MFMA GEMM tile, 2-phase double-buffered with COUNTED vmcnt:
// loads for step t+1 stay in flight across the barrier (T4 — never drain to
// 0 in the loop). 8 gload_lds per wave per stage.
// ---------------------------------------------------------------------------
__device__ __forceinline__ void gemm_tile(
    const u16* __restrict__ A, const u16* __restrict__ Bm,
    int lda, int ldb, int m0, int n0, int K,
    short* smem, f4_t acc[4][4], int tid)
{
  const int lane = tid & 63, w = tid >> 6;
  const int lo = lane & 15, hi = lane >> 4;
  const int wr = (w >> 1) * 64, wc = (w & 1) * 64;
  const int nsteps = K >> 6;

  auto STAGE = [&](int step, int buf) {
    int k0 = step * 64;
#pragma unroll
    for (int iss = 0; iss < 4; ++iss) {
      int bb = iss * 4096 + tid * 16;          // linear LDS byte
      int row = bb >> 7;                       // 128 B per row
      int lg = ((bb >> 4) & 7) ^ (row & 7);    // inverse-swizzled src granule
      gload16(A  + (size_t)(m0 + row) * lda + k0 + lg * 8,
              (char*)smem + buf * 16384 + iss * 4096 + w * 1024);
      gload16(Bm + (size_t)(n0 + row) * ldb + k0 + lg * 8,
              (char*)smem + 32768 + buf * 16384 + iss * 4096 + w * 1024);
    }
  };

  STAGE(0, 0);
  int cur = 0;
  for (int step = 0; step < nsteps; ++step) {
    if (step + 1 < nsteps) {
      STAGE(step + 1, cur ^ 1);                // 8 more loads in flight
      asm volatile("s_waitcnt vmcnt(8)\n\ts_barrier" ::: "memory");
    } else {
      asm volatile("s_waitcnt vmcnt(0)\n\ts_barrier" ::: "memory");
    }
    const short* As = (const short*)((char*)smem + cur * 16384);
    const short* Bs = (const short*)((char*)smem + 32768 + cur * 16384);
#pragma unroll
    for (int kk = 0; kk < 2; ++kk) {
      bf8_t af[4], bfr[4];
#pragma unroll
      for (int m = 0; m < 4; ++m) {
        int row = wr + m * 16 + lo;
        int g = (kk * 4 + hi) ^ (row & 7);
        af[m] = *(const bf8_t*)&As[row * 64 + g * 8];
      }
#pragma unroll
      for (int n = 0; n < 4; ++n) {
        int row = wc + n * 16 + lo;
        int g = (kk * 4 + hi) ^ (row & 7);
        bfr[n] = *(const bf8_t*)&Bs[row * 64 + g * 8];
      }
#pragma unroll
      for (int m = 0; m < 4; ++m)
#pragma unroll
        for (int n = 0; n < 4; ++n)
          acc[m][n] = MFMA(af[m], bfr[n], acc[m][n]);
    }
    asm volatile("s_barrier" ::: "memory");    // all waves done reading cur
    cur ^= 1;
  }
}

// ---------------------------------------------------------------------------
// K1: fp32 -> bf16 conversion of x and weights; zero entropy scalar.
// ---------------------------------------------------------------------------
__global__ __launch_bounds__(256)
void convert_kernel(const float* __restrict__ x,  const float* __restrict__ wq,
                    const float* __restrict__ wk, const float* __restrict__ wv,
                    const float* __restrict__ wo,
                    u16* xb, u16* wqb, u16* wkb, u16* wvb, u16* wob, float* ent)
{
  size_t i = (size_t)blockIdx.x * 256 + threadIdx.x;
  if (blockIdx.x == 0 && threadIdx.x == 0) *ent = 0.f;
  const float* src; u16* dst; size_t off;
  if (i < 524288) { src = x; dst = xb; off = i; }
  else {
    size_t r = i - 524288;
    int sel = (int)(r >> 17);
    off = r & 131071;
    src = sel == 0 ? wq : sel == 1 ? wk : sel == 2 ? wv : wo;
    dst = sel == 0 ? wqb : sel == 1 ? wkb : sel == 2 ? wvb : wob;
  }
  f4_t a = *(const f4_t*)&src[off * 8];
  f4_t c = *(const f4_t*)&src[off * 8 + 4];
  u16 t[8] = {f2bf(a[0]), f2bf(a[1]), f2bf(a[2]), f2bf(a[3]),
              f2bf(c[0]), f2bf(c[1]), f2bf(c[2]), f2bf(c[3])};
  *(uint4*)&dst[off * 8] = *(const uint4*)t;
}

// ---------------------------------------------------------------------------
// K2: fused QKV projection. Q (pre-scaled by 1/8), K -> [B,H,T,D];
// V -> transposed [B,H,D,T]. Epilogue through swizzled LDS, 16B stores.
// ---------------------------------------------------------------------------
__global__ __launch_bounds__(256)
void qkv_kernel(const u16* __restrict__ X, const u16* __restrict__ Wq,
                const u16* __restrict__ Wk, const u16* __restrict__ Wv,
                const float* __restrict__ bq, const float* __restrict__ bk,
                const float* __restrict__ bv,
                u16* Qo, u16* Ko, u16* Vto)
{
  __shared__ short smem[32768];            // 64KB: GEMM dbuf, then epilogue
  const int tid = threadIdx.x;
  const int nb = blockIdx.x;
  const int which = nb >> 3;
  const int n0 = (nb & 7) * 128;
  const int m0 = blockIdx.y * 128;
  const u16* W    = which == 0 ? Wq : which == 1 ? Wk : Wv;
  const float* bias = which == 0 ? bq : which == 1 ? bk : bv;

  f4_t acc[4][4];
#pragma unroll
  for (int m = 0; m < 4; ++m)
#pragma unroll
    for (int n = 0; n < 4; ++n) acc[m][n] = f4_t{0.f, 0.f, 0.f, 0.f};

  gemm_tile(X, W, 1024, 1024, m0, n0, 1024, smem, acc, tid);

  const int lane = tid & 63, w = tid >> 6;
  const int lo = lane & 15, hi = lane >> 4;
  const int wr = (w >> 1) * 64, wc = (w & 1) * 64;
  const float scl = (which == 0) ? 0.125f : 1.0f;   // fold att scale into Q
  char* ep = (char*)smem;
  const int bix = m0 >> 11, t0g = m0 & 2047;

  if (which < 2) {
    // stage [token r][feature c] bf16, 16B-granule XOR swizzle by (r&7)<<1
#pragma unroll
    for (int n = 0; n < 4; ++n) {
      int c = wc + n * 16 + lo;
      float bb = bias[n0 + c];
#pragma unroll
      for (int m = 0; m < 4; ++m)
#pragma unroll
        for (int j = 0; j < 4; ++j) {
          int r = wr + m * 16 + hi * 4 + j;
          int pg = (c >> 3) ^ ((r & 7) << 1);
          *(u16*)(ep + r * 256 + pg * 16 + (c & 7) * 2) =
              f2bf((acc[m][n][j] + bb) * scl);
        }
    }
    __syncthreads();
    u16* Out = (which == 0) ? Qo : Ko;
#pragma unroll
    for (int rep = 0; rep < 8; ++rep) {
      int r = rep * 16 + (tid >> 4);
      int seg = tid & 15;
      int pg = seg ^ ((r & 7) << 1);
      uint4 v = *(uint4*)(ep + r * 256 + pg * 16);  // cols seg*8..+7
      int hh = (n0 >> 6) + (seg >> 3);
      int d = (seg & 7) * 8;
      *(uint4*)&Out[(((size_t)bix * 16 + hh) * 2048 + t0g + r) * 64 + d] = v;
    }
  } else {
    // stage TRANSPOSED [feature c][token r] bf16 (pairs of tokens packed)
#pragma unroll
    for (int n = 0; n < 4; ++n) {
      int c = wc + n * 16 + lo;
      float bb = bias[n0 + c];
#pragma unroll
      for (int m = 0; m < 4; ++m)
#pragma unroll
        for (int jp = 0; jp < 2; ++jp) {
          int r = wr + m * 16 + hi * 4 + jp * 2;       // even
          u32 pk = cvtpk(acc[m][n][jp * 2] + bb, acc[m][n][jp * 2 + 1] + bb);
          int pg = (r >> 3) ^ ((c & 7) << 1);
          *(u32*)(ep + c * 256 + pg * 16 + (r & 7) * 2) = pk;
        }
    }
    __syncthreads();
#pragma unroll
    for (int rep = 0; rep < 8; ++rep) {
      int c = rep * 16 + (tid >> 4);
      int seg = tid & 15;
      int pg = seg ^ ((c & 7) << 1);
      uint4 v = *(uint4*)(ep + c * 256 + pg * 16);  // tokens seg*8..+7
      int f = n0 + c;
      int hh = f >> 6, d = f & 63;
      *(uint4*)&Vto[(((size_t)bix * 16 + hh) * 64 + d) * 2048 + t0g + seg * 8] = v;
    }
  }
}

// ---------------------------------------------------------------------------
// K3: causal flash attention, balanced + counted-vmcnt pipeline. grid = 512:
// block = (bh, q-tile pair {p, 31-p}) -> exactly 33 staged KV-tiles each.
// 4 waves share double-buffered K/V^T LDS (global_load_lds, XOR-swizzled);
// prefetch for tile t+1 stays in flight across the barrier (vmcnt(4)).
// Swapped QK^T / PV keeps softmax state lane-local; defer-max; Q pre-scaled.
// ---------------------------------------------------------------------------
__global__ __launch_bounds__(256, 4)
void attn_kernel(const u16* __restrict__ Qg, const u16* __restrict__ Kg,
                 const u16* __restrict__ Vtg, u16* __restrict__ Att,
                 float* __restrict__ Ent)
{
  __shared__ char smem[40960];   // K dbuf 16K | V dbuf 16K | P strips 8K
  const int tid = threadIdx.x, lane = tid & 63, w = tid >> 6;
  const int lo = lane & 15, hi = lane >> 4;
  const int n = blockIdx.x;
  const int bh = (n & 7) * 4 + ((n >> 3) & 3);   // 4 heads per XCD
  const int p = n >> 5;                          // 0..15 -> tiles {p, 31-p}
  const int b = bh >> 4, h = bh & 15;
  const u16* Qb  = Qg  + (size_t)bh * (2048 * 64);
  const u16* Kb  = Kg  + (size_t)bh * (2048 * 64);
  const u16* Vtb = Vtg + (size_t)bh * (64 * 2048);
  u16* Attp = Att + (size_t)b * (2048 * 1024) + h * 64;
  short* Pw = (short*)(smem + 32768 + w * 2048);   // [16 q][64 kv]

  auto STAGE = [&](int kt, int buf) {
#pragma unroll
    for (int iss = 0; iss < 2; ++iss) {
      int bb = iss * 4096 + tid * 16;
      int row = bb >> 7;                   // 0..63
      int lg = ((bb >> 4) & 7) ^ (row & 7);
      gload16(Kb + (size_t)(kt * 64 + row) * 64 + lg * 8,
              smem + buf * 8192 + iss * 4096 + w * 1024);
      gload16(Vtb + (size_t)row * 2048 + kt * 64 + lg * 8,
              smem + 16384 + buf * 8192 + iss * 4096 + w * 1024);
    }
  };

  float hs_total = 0.f;

  for (int ph = 0; ph < 2; ++ph) {
    const int g = ph ? (31 - p) : p;
    const int q0 = g * 64;
    const int nt = g + 1;
    const int qrow = q0 + w * 16 + lo;     // lane-local q row

    bf8_t qf[2];
#pragma unroll
    for (int kk = 0; kk < 2; ++kk)
      qf[kk] = *(const bf8_t*)&Qb[(size_t)qrow * 64 + kk * 32 + hi * 8];

    f4_t o[4];
#pragma unroll
    for (int md = 0; md < 4; ++md) o[md] = f4_t{0.f, 0.f, 0.f, 0.f};
    float m_ = -3.0e38f, l_ = 0.f, E_ = 0.f;   // l_, E_ per-lane partials

    STAGE(0, 0);
    int cur = 0;

    for (int kt = 0; kt < nt; ++kt) {
      if (kt + 1 < nt) {
        STAGE(kt + 1, cur ^ 1);            // 4 more loads in flight
        asm volatile("s_waitcnt vmcnt(4)\n\ts_barrier" ::: "memory");
      } else {
        asm volatile("s_waitcnt vmcnt(0)\n\ts_barrier" ::: "memory");
      }
      const short* KL = (const short*)(smem + cur * 8192);
      const short* VL = (const short*)(smem + 16384 + cur * 8192);

      // S' = K.Q^T: s[mk][j] at kv-local = mk*16+hi*4+j, q = qrow
      f4_t s[4];
#pragma unroll
      for (int mk = 0; mk < 4; ++mk) s[mk] = f4_t{0.f, 0.f, 0.f, 0.f};
#pragma unroll
      for (int kk = 0; kk < 2; ++kk) {
        bf8_t kf[4];
#pragma unroll
        for (int mk = 0; mk < 4; ++mk) {
          int row = mk * 16 + lo;
          int gg = (kk * 4 + hi) ^ (row & 7);
          kf[mk] = *(const bf8_t*)&KL[row * 64 + gg * 8];
        }
#pragma unroll
        for (int mk = 0; mk < 4; ++mk)
          s[mk] = MFMA(kf[mk], qf[kk], s[mk]);
      }

      // causal mask: only the last tile straddles the diagonal
      if (kt == nt - 1) {
#pragma unroll
        for (int mk = 0; mk < 4; ++mk)
#pragma unroll
          for (int jj = 0; jj < 4; ++jj)
            if ((mk * 16 + hi * 4 + jj) > (w * 16 + lo)) s[mk][jj] = -1.0e30f;
      }

      // row max (cross-lane) + defer-max rescale (THR=8)
      float mt = s[0][0];
#pragma unroll
      for (int mk = 0; mk < 4; ++mk)
#pragma unroll
        for (int jj = 0; jj < 4; ++jj) mt = fmaxf(mt, s[mk][jj]);
      mt = fmaxf(mt, __shfl_xor(mt, 16));
      mt = fmaxf(mt, __shfl_xor(mt, 32));
      if (!__all(mt <= m_ + 8.f)) {
        float mnew = fmaxf(m_, mt);
        float f = __expf(m_ - mnew);       // 0 on first tile
        l_ *= f; E_ *= f;
#pragma unroll
        for (int md = 0; md < 4; ++md) o[md] *= f;
        m_ = mnew;
      }
      // per-lane partial l/E (cross-lane reduction deferred to phase end)
      float pv16[16];
#pragma unroll
      for (int mk = 0; mk < 4; ++mk)
#pragma unroll
        for (int jj = 0; jj < 4; ++jj) {
          float pv = __expf(s[mk][jj] - m_);   // bounded by e^8
          pv16[mk * 4 + jj] = pv;
          l_ += pv; E_ += pv * s[mk][jj];      // 0 * -1e30 == -0, no NaN
        }

      // P^T row (q=lo) -> per-wave LDS strip (packed, swizzled)
#pragma unroll
      for (int mk = 0; mk < 4; ++mk) {
        u32 a = cvtpk(pv16[mk * 4 + 0], pv16[mk * 4 + 1]);
        u32 c = cvtpk(pv16[mk * 4 + 2], pv16[mk * 4 + 3]);
        int gg = (mk * 2 + (hi >> 1)) ^ (lo & 7);
        *(uint2*)&Pw[lo * 64 + gg * 8 + (hi & 1) * 4] = make_uint2(a, c);
      }

      // PV (swapped): o[md] += V^T(d x kv) . P^T(kv x q)
#pragma unroll
      for (int kh = 0; kh < 2; ++kh) {
        int gp = (kh * 4 + hi) ^ (lo & 7);
        bf8_t pf = *(const bf8_t*)&Pw[lo * 64 + gp * 8];
#pragma unroll
        for (int md = 0; md < 4; ++md) {
          int row = md * 16 + lo;
          int gv = (kh * 4 + hi) ^ (row & 7);
          bf8_t vf = *(const bf8_t*)&VL[row * 64 + gv * 8];
          o[md] = MFMA(vf, pf, o[md]);
        }
      }
      asm volatile("s_barrier" ::: "memory");  // all waves done reading cur
      cur ^= 1;
    }

    // deferred cross-lane l/E reduction (same q row lives in the 4 hi-lanes)
    l_ += __shfl_xor(l_, 16); l_ += __shfl_xor(l_, 32);
    E_ += __shfl_xor(E_, 16); E_ += __shfl_xor(E_, 32);

    // epilogue: normalize + bf16 store (8B per lane per md)
    float invl = 1.0f / l_;
#pragma unroll
    for (int md = 0; md < 4; ++md) {
      u32 w0 = cvtpk(o[md][0] * invl, o[md][1] * invl);
      u32 w1 = cvtpk(o[md][2] * invl, o[md][3] * invl);
      *(uint2*)&Attp[(size_t)qrow * 1024 + md * 16 + hi * 4] =
          make_uint2(w0, w1);
    }
    // entropy: H = m + log(l) - E/l per row; one contributor per row (hi==0)
    hs_total += (hi == 0) ? (m_ + __logf(l_) - E_ * invl) : 0.f;
  }

  float hs = hs_total;
#pragma unroll
  for (int off = 1; off < 64; off <<= 1) hs += __shfl_xor(hs, off);
  if (lane == 0) atomicAdd(Ent, hs * (1.0f / 65536.0f));
}

// ---------------------------------------------------------------------------
// K4: output projection, fp32 out. Two-pass LDS-transposed epilogue so
// stores are coalesced 16B. grid = (8, 32).
// ---------------------------------------------------------------------------
__global__ __launch_bounds__(256)
void proj_kernel(const u16* __restrict__ Attb, const u16* __restrict__ Wo,
                 const float* __restrict__ bo, float* __restrict__ Out)
{
  __shared__ short smem[32768];
  const int tid = threadIdx.x;
  const int n0 = blockIdx.x * 128;
  const int m0 = blockIdx.y * 128;

  f4_t acc[4][4];
#pragma unroll
  for (int m = 0; m < 4; ++m)
#pragma unroll
    for (int n = 0; n < 4; ++n) acc[m][n] = f4_t{0.f, 0.f, 0.f, 0.f};

  gemm_tile(Attb, Wo, 1024, 1024, m0, n0, 1024, smem, acc, tid);

  const int lane = tid & 63, w = tid >> 6;
  const int lo = lane & 15, hi = lane >> 4;
  const int wc = (w & 1) * 64;
  float* ep = (float*)smem;                // [64 rows][128 cols] f32 per pass

#pragma unroll
  for (int pass = 0; pass < 2; ++pass) {
    __syncthreads();                       // guards smem reuse
    if ((w >> 1) == pass) {
#pragma unroll
      for (int n = 0; n < 4; ++n) {
        int c = wc + n * 16 + lo;
        float bb = bo[n0 + c];
#pragma unroll
        for (int m = 0; m < 4; ++m)
#pragma unroll
          for (int j = 0; j < 4; ++j) {
            int r = m * 16 + hi * 4 + j;   // 0..63
            int pg = (c >> 2) ^ ((r & 7) << 2);
            ep[r * 128 + pg * 4 + (c & 3)] = acc[m][n][j] + bb;
          }
      }
    }
    __syncthreads();
    int r = tid >> 2, q = tid & 3;
#pragma unroll
    for (int i = 0; i < 8; ++i) {
      int g = q * 8 + i;
      int pg = g ^ ((r & 7) << 2);
      f4_t v = *(f4_t*)&ep[r * 128 + pg * 4];
      *(f4_t*)&Out[(size_t)(m0 + pass * 64 + r) * 1024 + n0 + g * 4] = v;
    }
  }
}

// ---------------------------------------------------------------------------
extern "C" void kernel_launch(void* const* d_in, const int* in_sizes, int n_in,
                              void* d_out, int out_size, void* d_ws, size_t ws_size,
                              hipStream_t stream)
{
  const float* x  = (const float*)d_in[0];
  // d_in[1] = causal mask (structure hard-coded)
  const float* wq = (const float*)d_in[2];
  const float* bq = (const float*)d_in[3];
  const float* wk = (const float*)d_in[4];
  const float* bk = (const float*)d_in[5];
  const float* wv = (const float*)d_in[6];
  const float* bv = (const float*)d_in[7];
  const float* wo = (const float*)d_in[8];
  const float* bo = (const float*)d_in[9];

  float* out = (float*)d_out;
  float* ent = out + (size_t)2 * 2048 * 1024;

  char* ws = (char*)d_ws;
  u16* xb   = (u16*)ws;                               // 8 MB  (4096x1024)
  u16* wqb  = (u16*)(ws + 8388608);                   // 2 MB each
  u16* wkb  = (u16*)(ws + 8388608 + 2097152);
  u16* wvb  = (u16*)(ws + 8388608 + 2 * 2097152);
  u16* wob  = (u16*)(ws + 8388608 + 3 * 2097152);
  u16* Qb   = (u16*)(ws + 16777216);                  // 8 MB, [B,H,T,D] (x1/8)
  u16* Kb   = (u16*)(ws + 16777216 + 8388608);        // 8 MB, [B,H,T,D]
  u16* Vtb  = (u16*)(ws + 16777216 + 2 * 8388608);    // 8 MB, [B,H,D,T]
  u16* Attb = (u16*)(ws + 16777216 + 3 * 8388608);    // 8 MB, [B,T,C]

  convert_kernel<<<4096, 256, 0, stream>>>(x, wq, wk, wv, wo,
                                           xb, wqb, wkb, wvb, wob, ent);
  qkv_kernel<<<dim3(24, 32), 256, 0, stream>>>(xb, wqb, wkb, wvb,
                                               bq, bk, bv, Qb, Kb, Vtb);
  attn_kernel<<<512, 256, 0, stream>>>(Qb, Kb, Vtb, Attb, ent);
  proj_kernel<<<dim3(8, 32), 256, 0, stream>>>(Attb, wob, bo, out);
}